// Round 4
// baseline (272.156 us; speedup 1.0000x reference)
//
#include <hip/hip_runtime.h>
#include <hip/hip_bf16.h>
#include <stdint.h>

// Problem constants (from reference)
#define S_  32
#define P_  48
#define T_  8
#define E_  64
#define H_  64
#define D1_ 512
#define D2_ 1024
#define B_  (S_*P_)        // 1536
#define M_  (S_*P_*P_)     // 73728 rows of the big GEMMs
#define K1_ 576            // T*E + H
#define KE_ 512            // T*E

typedef __attribute__((ext_vector_type(8))) short  short8;
typedef __attribute__((ext_vector_type(8))) __bf16 bf16x8;
typedef __attribute__((ext_vector_type(4))) float  f32x4;
typedef __attribute__((ext_vector_type(8))) float  f32x8;

// fp32 -> bf16 (round to nearest even), bit carrier = short
__device__ inline short f2bf(float x) {
  union { float f; unsigned u; } v; v.f = x;
  unsigned r = v.u + 0x7FFFu + ((v.u >> 16) & 1u);
  return (short)(r >> 16);
}

// async global->LDS, 16 bytes per lane (wave-uniform LDS base + lane*16; the
// GLOBAL source address is per-lane -> T2 swizzle done by pre-swizzling source)
__device__ inline void async16(const void* g, void* l) {
  __builtin_amdgcn_global_load_lds(
      (const __attribute__((address_space(1))) void*)g,
      (__attribute__((address_space(3))) void*)l, 16, 0, 0);
}

__device__ inline f32x4 mfma16(short8 a, short8 b, f32x4 c) {
  return __builtin_amdgcn_mfma_f32_16x16x32_bf16(
      __builtin_bit_cast(bf16x8, a), __builtin_bit_cast(bf16x8, b), c, 0, 0, 0);
}

// ---------------------------------------------------------------- K0: weights -> bf16
__global__ __launch_bounds__(256) void k_cvt_w(const float* __restrict__ W1,
                                               const float* __restrict__ W2,
                                               short* __restrict__ W1b,
                                               short* __restrict__ W2b) {
  int idx = blockIdx.x * 256 + threadIdx.x;
  if (idx < D1_ * K1_) W1b[idx] = f2bf(W1[idx]);
  int idx2 = idx - D1_ * K1_;
  if (idx2 >= 0 && idx2 < D2_ * D1_) W2b[idx2] = f2bf(W2[idx2]);
}

// ---------------------------------------------------------------- K0b: oW[p][n] = obs[p] @ Wse^T  (fp32)
__global__ __launch_bounds__(256) void k_oW(const float* __restrict__ traj,
                                            const float* __restrict__ Wse,
                                            float* __restrict__ oW) {
  int bid = blockIdx.x;                 // 1536*2 blocks
  int p = bid >> 1;
  int n = ((bid & 1) << 8) + threadIdx.x;
  float obs[16];
#pragma unroll
  for (int t = 0; t < T_; ++t) {
    obs[2*t]   = traj[(t*B_ + p)*2 + 0];
    obs[2*t+1] = traj[(t*B_ + p)*2 + 1];
  }
  float acc = 0.f;
#pragma unroll
  for (int k = 0; k < 16; ++k) acc += obs[k] * Wse[n*16 + k];
  oW[p*KE_ + n] = acc;
}

// ---------------------------------------------------------------- K1: build X (bf16)
// X[row=(s,i,j)][n<512]  = tw[s,rem,n&1,n>>6] * (oW[bj][n] - oW[bi][n] + bse[n])
// X[row][n>=512]         = h[bj][n-512]
__global__ __launch_bounds__(256) void k_build_x(const float* __restrict__ tw,
                                                 const float* __restrict__ h,
                                                 const float* __restrict__ bse,
                                                 const float* __restrict__ oW,
                                                 short* __restrict__ X) {
  int tid = threadIdx.x;
  int wid = tid >> 6, lane = tid & 63;
  int row = blockIdx.x * 4 + wid;
  int s   = row / (P_ * P_);
  int rem = row - s * (P_ * P_);
  int i   = rem / P_;
  int j   = rem - i * P_;
  int bi = s * P_ + i, bj = s * P_ + j;

  const float* twq = tw + (size_t)(s * (P_*P_) + rem) * 16;  // [2][8]
  int t = lane >> 3;                 // n>>6 for this lane's 8-elem chunk
  float w0 = twq[t];                 // c = 0 (even n)
  float w1 = twq[8 + t];             // c = 1 (odd n)

  int n0 = lane * 8;
  f32x8 vj = *(const f32x8*)&oW[(size_t)bj * KE_ + n0];
  f32x8 vi = *(const f32x8*)&oW[(size_t)bi * KE_ + n0];
  f32x8 vb = *(const f32x8*)&bse[n0];
  short8 o;
#pragma unroll
  for (int k = 0; k < 8; ++k) {
    float e = (vj[k] - vi[k] + vb[k]) * ((k & 1) ? w1 : w0);
    o[k] = f2bf(e);
  }
  *(short8*)&X[(size_t)row * K1_ + n0] = o;

  if (lane < 8) {                    // h tail: 64 elems = 8 lanes x short8
    f32x8 vh = *(const f32x8*)&h[(size_t)bj * H_ + lane * 8];
    short8 oh;
#pragma unroll
    for (int k = 0; k < 8; ++k) oh[k] = f2bf(vh[k]);
    *(short8*)&X[(size_t)row * K1_ + KE_ + lane * 8] = oh;
  }
}

// ---------------------------------------------------------------- K2: GEMM1 + relu
// X1 = relu(X[73728x576] @ W1b[512x576]^T + b1), bf16 out
// BM=256 BN=256 BK=64, 8 waves (2M x 4N), wave tile 128x64.
// T3-minimal schedule: stage(t+1) -> compute(t) -> vmcnt(0) -> s_barrier.
__global__ __launch_bounds__(512, 2) void k_gemm1(const short* __restrict__ X,
                                                  const short* __restrict__ W1b,
                                                  const float* __restrict__ b1,
                                                  short* __restrict__ X1) {
  __shared__ short Abuf[2][256 * 64];
  __shared__ short Bbuf[2][256 * 64];
  int tid = threadIdx.x;
  int wid = tid >> 6, lane = tid & 63;
  // T1: grid 576 = 8 * 72; adjacent wgid (same XCD) share the A-panel (tn pair)
  int wgid = (blockIdx.x & 7) * 72 + (blockIdx.x >> 3);
  int tm = wgid >> 1, tn = wgid & 1;
  int brow = tm * 256, bcol = tn * 256;
  int wr = wid >> 2, wc = wid & 3;       // 2M x 4N
  int lr = lane & 15, lhi = lane >> 4;
  int sx = lr & 7;                       // T2 read-side XOR (row&7 == lr&7)

  f32x4 acc[8][4];
#pragma unroll
  for (int m = 0; m < 8; ++m)
#pragma unroll
    for (int n = 0; n < 4; ++n) acc[m][n] = (f32x4){0.f, 0.f, 0.f, 0.f};

  auto stage = [&](int buf, int k0) {
#pragma unroll
    for (int it = 0; it < 4; ++it) {     // A: 256x64 = 2048 granules / 512 thr
      int fg = it * 512 + tid;
      int r = fg >> 3, gs = (fg & 7) ^ (r & 7);
      async16(&X  [(size_t)(brow + r) * K1_ + k0 + (gs << 3)], &Abuf[buf][fg * 8]);
    }
#pragma unroll
    for (int it = 0; it < 4; ++it) {     // B: 256x64
      int fg = it * 512 + tid;
      int r = fg >> 3, gs = (fg & 7) ^ (r & 7);
      async16(&W1b[(size_t)(bcol + r) * K1_ + k0 + (gs << 3)], &Bbuf[buf][fg * 8]);
    }
  };
  auto compute = [&](int buf) {
#pragma unroll
    for (int kk = 0; kk < 2; ++kk) {
      int gr = kk * 4 + lhi;
      short8 a[8], b[4];
#pragma unroll
      for (int m = 0; m < 8; ++m)
        a[m] = *(const short8*)&Abuf[buf][(wr*128 + m*16 + lr) * 64 + ((gr ^ sx) << 3)];
#pragma unroll
      for (int n = 0; n < 4; ++n)
        b[n] = *(const short8*)&Bbuf[buf][(wc*64 + n*16 + lr) * 64 + ((gr ^ sx) << 3)];
      __builtin_amdgcn_s_setprio(1);
#pragma unroll
      for (int m = 0; m < 8; ++m)
#pragma unroll
        for (int n = 0; n < 4; ++n)
          acc[m][n] = mfma16(a[m], b[n], acc[m][n]);
      __builtin_amdgcn_s_setprio(0);
    }
  };

  // prologue
  stage(0, 0);
  asm volatile("s_waitcnt vmcnt(0)" ::: "memory");
  __builtin_amdgcn_s_barrier();
  // main loop: 9 K-steps
  for (int t = 0; t < 9; ++t) {
    int cur = t & 1;
    if (t + 1 < 9) stage(cur ^ 1, (t + 1) * 64);   // issue BEFORE compute
    compute(cur);
    asm volatile("s_waitcnt vmcnt(0)" ::: "memory"); // drain AFTER compute
    __builtin_amdgcn_s_barrier();
  }

  // epilogue: bias + relu, bf16 store. C/D: row=(lane>>4)*4+q, col=lane&15
#pragma unroll
  for (int n = 0; n < 4; ++n) {
    int gcol = bcol + wc*64 + n*16 + lr;
    float bias = b1[gcol];
#pragma unroll
    for (int m = 0; m < 8; ++m) {
      int grow0 = brow + wr*128 + m*16 + lhi*4;
#pragma unroll
      for (int q = 0; q < 4; ++q) {
        float v = acc[m][n][q] + bias;
        v = v > 0.f ? v : 0.f;
        X1[(size_t)(grow0 + q) * D1_ + gcol] = f2bf(v);
      }
    }
  }
}

// ---------------------------------------------------------------- K3: GEMM2 + relu + max over j
// BM=192 (4 j-groups), BN=256, 8 waves (2M x 4N), wave tile 96x64 (2 groups).
// Same T3-minimal schedule. Epilogue: per-group max + shfl(16,32).
__global__ __launch_bounds__(512, 2) void k_gemm2(const short* __restrict__ X1,
                                                  const short* __restrict__ W2b,
                                                  const float* __restrict__ b2,
                                                  float* __restrict__ out) {
  __shared__ short Abuf[2][192 * 64];
  __shared__ short Bbuf[2][256 * 64];
  int tid = threadIdx.x;
  int wid = tid >> 6, lane = tid & 63;
  // T1: grid 1536 = 8 * 192
  int wgid = (blockIdx.x & 7) * 192 + (blockIdx.x >> 3);
  int tm = wgid >> 2, tn = wgid & 3;
  int brow = tm * 192, bcol = tn * 256;
  int wr = wid >> 2, wc = wid & 3;
  int lr = lane & 15, lhi = lane >> 4;
  int sx = lr & 7;

  f32x4 acc[6][4];
#pragma unroll
  for (int m = 0; m < 6; ++m)
#pragma unroll
    for (int n = 0; n < 4; ++n) acc[m][n] = (f32x4){0.f, 0.f, 0.f, 0.f};

  auto stage = [&](int buf, int k0) {
#pragma unroll
    for (int it = 0; it < 3; ++it) {     // A: 192x64 = 1536 granules
      int fg = it * 512 + tid;
      int r = fg >> 3, gs = (fg & 7) ^ (r & 7);
      async16(&X1 [(size_t)(brow + r) * D1_ + k0 + (gs << 3)], &Abuf[buf][fg * 8]);
    }
#pragma unroll
    for (int it = 0; it < 4; ++it) {     // B: 256x64 = 2048 granules
      int fg = it * 512 + tid;
      int r = fg >> 3, gs = (fg & 7) ^ (r & 7);
      async16(&W2b[(size_t)(bcol + r) * D1_ + k0 + (gs << 3)], &Bbuf[buf][fg * 8]);
    }
  };
  auto compute = [&](int buf) {
#pragma unroll
    for (int kk = 0; kk < 2; ++kk) {
      int gr = kk * 4 + lhi;
      short8 a[6], b[4];
#pragma unroll
      for (int m = 0; m < 6; ++m)
        a[m] = *(const short8*)&Abuf[buf][(wr*96 + m*16 + lr) * 64 + ((gr ^ sx) << 3)];
#pragma unroll
      for (int n = 0; n < 4; ++n)
        b[n] = *(const short8*)&Bbuf[buf][(wc*64 + n*16 + lr) * 64 + ((gr ^ sx) << 3)];
      __builtin_amdgcn_s_setprio(1);
#pragma unroll
      for (int m = 0; m < 6; ++m)
#pragma unroll
        for (int n = 0; n < 4; ++n)
          acc[m][n] = mfma16(a[m], b[n], acc[m][n]);
      __builtin_amdgcn_s_setprio(0);
    }
  };

  stage(0, 0);
  asm volatile("s_waitcnt vmcnt(0)" ::: "memory");
  __builtin_amdgcn_s_barrier();
  for (int t = 0; t < 8; ++t) {          // D1/64 = 8 K-steps
    int cur = t & 1;
    if (t + 1 < 8) stage(cur ^ 1, (t + 1) * 64);
    compute(cur);
    asm volatile("s_waitcnt vmcnt(0)" ::: "memory");
    __builtin_amdgcn_s_barrier();
  }

  // epilogue: wave rows = 2 j-groups (m 0..2 and 3..5); max + shfl reduce
  int gbase = tm * 4 + wr * 2;
#pragma unroll
  for (int n = 0; n < 4; ++n) {
    int gcol = bcol + wc*64 + n*16 + lr;
    float bias = b2[gcol];
    float r0 = 0.f, r1 = 0.f;            // relu floor == identity for max(relu)
#pragma unroll
    for (int m = 0; m < 3; ++m)
#pragma unroll
      for (int q = 0; q < 4; ++q) {
        float v0 = acc[m][n][q] + bias;
        float v1 = acc[m + 3][n][q] + bias;
        if (v0 > r0) r0 = v0;
        if (v1 > r1) r1 = v1;
      }
    r0 = fmaxf(r0, __shfl_xor(r0, 16));
    r0 = fmaxf(r0, __shfl_xor(r0, 32));
    r1 = fmaxf(r1, __shfl_xor(r1, 16));
    r1 = fmaxf(r1, __shfl_xor(r1, 32));
    if (lhi == 0) {
      out[(size_t)gbase       * D2_ + gcol] = r0;
      out[(size_t)(gbase + 1) * D2_ + gcol] = r1;
    }
  }
}

// ----------------------------------------------------------------
extern "C" void kernel_launch(void* const* d_in, const int* in_sizes, int n_in,
                              void* d_out, int out_size, void* d_ws, size_t ws_size,
                              hipStream_t stream) {
  const float* h_states = (const float*)d_in[0];
  const float* traj = (const float*)d_in[3];
  const float* tw   = (const float*)d_in[4];
  const float* Wse  = (const float*)d_in[6];
  const float* bse  = (const float*)d_in[7];
  const float* W1   = (const float*)d_in[8];
  const float* b1   = (const float*)d_in[9];
  const float* W2   = (const float*)d_in[10];
  const float* b2   = (const float*)d_in[11];
  float* out = (float*)d_out;

  char* ws = (char*)d_ws;
  const size_t X_BYTES   = (size_t)M_ * K1_ * 2;   // 84,934,656
  const size_t X1_BYTES  = (size_t)M_ * D1_ * 2;   // 75,497,472
  const size_t W1B_BYTES = (size_t)D1_ * K1_ * 2;  //    589,824
  short* X   = (short*)ws;
  short* X1  = (short*)(ws + X_BYTES);
  short* W1b = (short*)(ws + X_BYTES + X1_BYTES);
  short* W2b = (short*)(ws + X_BYTES + X1_BYTES + W1B_BYTES);
  // oW (3 MB fp32) aliases head of X1: consumed by k_build_x before k_gemm1
  float* oW  = (float*)(ws + X_BYTES);

  k_cvt_w  <<<(D1_*K1_ + D2_*D1_ + 255) / 256, 256, 0, stream>>>(W1, W2, W1b, W2b);
  k_oW     <<<B_ * 2, 256, 0, stream>>>(traj, Wse, oW);
  k_build_x<<<M_ / 4, 256, 0, stream>>>(tw, h_states, bse, oW, X);
  k_gemm1  <<<(M_ / 256) * (D1_ / 256), 512, 0, stream>>>(X, W1b, b1, X1);
  k_gemm2  <<<(M_ / 192) * (D2_ / 256), 512, 0, stream>>>(X1, W2b, b2, out);
}